// Round 1
// baseline (414.287 us; speedup 1.0000x reference)
//
#include <hip/hip_runtime.h>
#include <hip/hip_bf16.h>
#include <cstdint>

#define B_SZ   2
#define S_LEN  2048
#define C_LEN  2048
#define T_LEN  4096
#define EMB_   1024
#define HEADS_ 16
#define D_     64

typedef __attribute__((ext_vector_type(8))) short bf16x8;
typedef __attribute__((ext_vector_type(4))) float f32x4;

__device__ __forceinline__ unsigned short f2bf(float f) {
    unsigned u = __builtin_bit_cast(unsigned, f);
    u += 0x7fffu + ((u >> 16) & 1u);
    return (unsigned short)(u >> 16);
}
__device__ __forceinline__ float bf2f(unsigned short h) {
    return __builtin_bit_cast(float, (unsigned)h << 16);
}

// ---------------------------------------------------------------- xcb build
__global__ void build_xcb_k(const float* __restrict__ x, const float* __restrict__ ctx,
                            unsigned short* __restrict__ xcb) {
    int i = blockIdx.x * blockDim.x + threadIdx.x;      // one 8-elem chunk
    size_t e8 = (size_t)i * 8;
    int b = (int)(e8 / ((size_t)T_LEN * EMB_));
    size_t rem = e8 % ((size_t)T_LEN * EMB_);
    int t = (int)(rem / EMB_);
    int c = (int)(rem % EMB_);
    const float* src = (t < S_LEN)
        ? &x[((size_t)b * S_LEN + t) * EMB_ + c]
        : &ctx[((size_t)b * C_LEN + (t - S_LEN)) * EMB_ + c];
    float4 v0 = ((const float4*)src)[0];
    float4 v1 = ((const float4*)src)[1];
    uint4 o;
    o.x = (unsigned)f2bf(v0.x) | ((unsigned)f2bf(v0.y) << 16);
    o.y = (unsigned)f2bf(v0.z) | ((unsigned)f2bf(v0.w) << 16);
    o.z = (unsigned)f2bf(v1.x) | ((unsigned)f2bf(v1.y) << 16);
    o.w = (unsigned)f2bf(v1.z) | ((unsigned)f2bf(v1.w) << 16);
    *(uint4*)&xcb[e8] = o;
}

// ------------------------------------------------- weight transpose+convert
__global__ void wtrans_k(const float* __restrict__ W, unsigned short* __restrict__ WT) {
    __shared__ __align__(16) unsigned short tile[64][72];
    int bx = blockIdx.x, by = blockIdx.y;   // bx: n-tile, by: k-tile
    int tid = threadIdx.x;
#pragma unroll
    for (int r = 0; r < 4; ++r) {
        int idx = tid + r * 256;
        int row = idx >> 4, c4 = idx & 15;
        float4 v = ((const float4*)&W[((size_t)(by * 64 + row)) * EMB_ + bx * 64])[c4];
        tile[row][c4 * 4 + 0] = f2bf(v.x);
        tile[row][c4 * 4 + 1] = f2bf(v.y);
        tile[row][c4 * 4 + 2] = f2bf(v.z);
        tile[row][c4 * 4 + 3] = f2bf(v.w);
    }
    __syncthreads();
#pragma unroll
    for (int r = 0; r < 2; ++r) {
        int idx = tid + r * 256;
        int n = idx >> 3, k8 = idx & 7;
        uint4 o;
        unsigned q[4];
#pragma unroll
        for (int j = 0; j < 4; ++j)
            q[j] = (unsigned)tile[k8 * 8 + 2 * j][n] | ((unsigned)tile[k8 * 8 + 2 * j + 1][n] << 16);
        o.x = q[0]; o.y = q[1]; o.z = q[2]; o.w = q[3];
        *(uint4*)&WT[((size_t)(bx * 64 + n)) * EMB_ + by * 64 + k8 * 8] = o;
    }
}

// ---------------------------------------------------------------- GEMM (m97-style)
// C[m][n] = sum_k A[m][k] * Bt[n][k];   A rows come from chunked mapping.
template <bool F32OUT>
__global__ __launch_bounds__(256) void gemm_bt_k(
    const unsigned short* __restrict__ A,
    const unsigned short* __restrict__ Bt,
    void* __restrict__ Cout,
    const float* __restrict__ bias,
    int mtiles_per_chunk, int chunk_stride) {
    constexpr int KTOT = 1024, NTOT = 1024;
    __shared__ __align__(16) unsigned short As[128 * 32];
    __shared__ __align__(16) unsigned short Bs[128 * 32];
    int nt = blockIdx.x, mt = blockIdx.y;
    int in_row0 = (mt / mtiles_per_chunk) * chunk_stride + (mt % mtiles_per_chunk) * 128;
    int out_row0 = mt * 128;
    int tid = threadIdx.x, w = tid >> 6, l = tid & 63, l15 = l & 15, lg = l >> 4;
    int wr = (w >> 1) * 64, wc = (w & 1) * 64;

    f32x4 zero4 = {0.f, 0.f, 0.f, 0.f};
    f32x4 acc[4][4];
#pragma unroll
    for (int i = 0; i < 4; ++i)
#pragma unroll
        for (int j = 0; j < 4; ++j) acc[i][j] = zero4;

    for (int k0 = 0; k0 < KTOT; k0 += 32) {
#pragma unroll
        for (int j = 0; j < 2; ++j) {
            int o = tid * 16 + j * 4096;        // byte offset in 8KB tile
            int row = o >> 6;                   // 64B per row (32 bf16)
            int ke = (o & 63) >> 1;             // element offset in row
            __builtin_amdgcn_global_load_lds(
                (const __attribute__((address_space(1))) void*)&A[(size_t)(in_row0 + row) * KTOT + k0 + ke],
                (__attribute__((address_space(3))) void*)&As[o >> 1], 16, 0, 0);
            __builtin_amdgcn_global_load_lds(
                (const __attribute__((address_space(1))) void*)&Bt[(size_t)(nt * 128 + row) * KTOT + k0 + ke],
                (__attribute__((address_space(3))) void*)&Bs[o >> 1], 16, 0, 0);
        }
        __syncthreads();
        bf16x8 af[4], bf[4];
#pragma unroll
        for (int fr = 0; fr < 4; ++fr)
            af[fr] = *(const bf16x8*)&As[(wr + fr * 16 + l15) * 32 + lg * 8];
#pragma unroll
        for (int fc = 0; fc < 4; ++fc)
            bf[fc] = *(const bf16x8*)&Bs[(wc + fc * 16 + l15) * 32 + lg * 8];
#pragma unroll
        for (int fr = 0; fr < 4; ++fr)
#pragma unroll
            for (int fc = 0; fc < 4; ++fc)
                acc[fr][fc] = __builtin_amdgcn_mfma_f32_16x16x32_bf16(af[fr], bf[fc], acc[fr][fc], 0, 0, 0);
        __syncthreads();
    }
#pragma unroll
    for (int fr = 0; fr < 4; ++fr) {
#pragma unroll
        for (int fc = 0; fc < 4; ++fc) {
            int row = out_row0 + wr + fr * 16 + lg * 4;
            int col = nt * 128 + wc + fc * 16 + l15;
#pragma unroll
            for (int i = 0; i < 4; ++i) {
                float v = acc[fr][fc][i];
                if (F32OUT) {
                    ((float*)Cout)[(size_t)(row + i) * NTOT + col] = v + bias[col];
                } else {
                    ((unsigned short*)Cout)[(size_t)(row + i) * NTOT + col] = f2bf(v);
                }
            }
        }
    }
}

// -------------------------------------------------- per-head LayerNorm (+scale)
__global__ void ln_head_k(const unsigned short* __restrict__ Y,
                          unsigned short* __restrict__ Out,
                          const float* __restrict__ lw, const float* __restrict__ lb,
                          int rows_per_b, float scale) {
    int gw = blockIdx.x * 4 + (threadIdx.x >> 6);
    int lane = threadIdx.x & 63;
    int h = gw % HEADS_;
    int row = gw / HEADS_;                   // [0, B*rows_per_b)
    int b = row / rows_per_b, r = row % rows_per_b;
    float v = bf2f(Y[(size_t)row * EMB_ + h * 64 + lane]);
    float s = v, s2 = v * v;
#pragma unroll
    for (int m = 1; m <= 32; m <<= 1) {
        s += __shfl_xor(s, m);
        s2 += __shfl_xor(s2, m);
    }
    float mu = s * (1.f / 64.f);
    float var = s2 * (1.f / 64.f) - mu * mu;
    float o = (v - mu) * rsqrtf(var + 1e-5f) * lw[lane] + lb[lane];
    Out[(((size_t)b * HEADS_ + h) * rows_per_b + r) * 64 + lane] = f2bf(o * scale);
}

// ---------------------------------------------------- V transpose [B,H,D,T]
__global__ void vtrans_k(const unsigned short* __restrict__ Yv, unsigned short* __restrict__ VT) {
    __shared__ __align__(16) unsigned short tile[64][72];
    int t0 = blockIdx.x * 64;
    int bh = blockIdx.y;
    int b = bh >> 4, h = bh & 15;
    int tid = threadIdx.x;
#pragma unroll
    for (int r = 0; r < 2; ++r) {
        int idx = tid + r * 256;
        int row = idx >> 3, c8 = idx & 7;
        uint4 v = *(const uint4*)&Yv[((size_t)b * T_LEN + t0 + row) * EMB_ + h * 64 + c8 * 8];
        *(uint4*)&tile[row][c8 * 8] = v;
    }
    __syncthreads();
#pragma unroll
    for (int r = 0; r < 2; ++r) {
        int idx = tid + r * 256;
        int d = idx >> 3, t8 = idx & 7;
        uint4 o;
        unsigned q[4];
#pragma unroll
        for (int j = 0; j < 4; ++j)
            q[j] = (unsigned)tile[t8 * 8 + 2 * j][d] | ((unsigned)tile[t8 * 8 + 2 * j + 1][d] << 16);
        o.x = q[0]; o.y = q[1]; o.z = q[2]; o.w = q[3];
        *(uint4*)&VT[((size_t)bh * 64 + d) * T_LEN + t0 + t8 * 8] = o;
    }
}

// ---------------------------------------------------------- flash attention
__global__ __launch_bounds__(256) void attn_k(
    const unsigned short* __restrict__ Q,    // [B,H,S,64]
    const unsigned short* __restrict__ K,    // [B,H,T,64]
    const unsigned short* __restrict__ VT,   // [B,H,64,T]
    const float* __restrict__ mask,          // [B,S]
    const float* __restrict__ cmask,         // [B,C]
    unsigned short* __restrict__ O) {        // [B,S,EMB]
    __shared__ __align__(16) unsigned short Ks[64][72];
    __shared__ __align__(16) unsigned short Vs[64][72];
    __shared__ __align__(16) unsigned short Ps[4][16][72];
    int qb = blockIdx.x, bh = blockIdx.y;
    int b = bh >> 4, h = bh & 15;
    int tid = threadIdx.x, w = tid >> 6, l = tid & 63, l15 = l & 15, lg = l >> 4;

    const unsigned short* Qb = Q + (size_t)bh * S_LEN * 64;
    const unsigned short* Kb = K + (size_t)bh * T_LEN * 64;
    const unsigned short* Vb = VT + (size_t)bh * 64 * T_LEN;

    int qrow = qb * 64 + w * 16;             // wave's first q row (local to b)
    bf16x8 qf0 = *(const bf16x8*)&Qb[(size_t)(qrow + l15) * 64 + lg * 8];
    bf16x8 qf1 = *(const bf16x8*)&Qb[(size_t)(qrow + l15) * 64 + lg * 8 + 32];

    float mrow[4];
#pragma unroll
    for (int i = 0; i < 4; ++i)
        mrow[i] = mask[(size_t)b * S_LEN + qrow + lg * 4 + i];

    f32x4 zero4 = {0.f, 0.f, 0.f, 0.f};
    f32x4 accO[4];
    float mM[4], lS[4];
#pragma unroll
    for (int i = 0; i < 4; ++i) { accO[i] = zero4; mM[i] = -__builtin_inff(); lS[i] = 0.f; }

    for (int kt = 0; kt < T_LEN / 64; ++kt) {
        const uint4* Ksrc = (const uint4*)&Kb[(size_t)kt * 64 * 64];
#pragma unroll
        for (int j = 0; j < 2; ++j) {
            int c = tid + j * 256;
            int vd = c >> 3, vc = c & 7;
            uint4 kv = Ksrc[c];
            *(uint4*)&Ks[vd][vc * 8] = kv;
            uint4 vv = *(const uint4*)&Vb[(size_t)vd * T_LEN + kt * 64 + vc * 8];
            *(uint4*)&Vs[vd][vc * 8] = vv;
        }
        __syncthreads();

        // S = Q K^T  (C-layout: col t = nf*16+l15, row q = lg*4+i)
        f32x4 sa[4];
#pragma unroll
        for (int nf = 0; nf < 4; ++nf) {
            sa[nf] = zero4;
            bf16x8 kf0 = *(const bf16x8*)&Ks[nf * 16 + l15][lg * 8];
            bf16x8 kf1 = *(const bf16x8*)&Ks[nf * 16 + l15][lg * 8 + 32];
            sa[nf] = __builtin_amdgcn_mfma_f32_16x16x32_bf16(qf0, kf0, sa[nf], 0, 0, 0);
            sa[nf] = __builtin_amdgcn_mfma_f32_16x16x32_bf16(qf1, kf1, sa[nf], 0, 0, 0);
        }

        float mc[4];
#pragma unroll
        for (int nf = 0; nf < 4; ++nf) {
            int t = kt * 64 + nf * 16 + l15;
            mc[nf] = (t < S_LEN) ? mask[(size_t)b * S_LEN + t]
                                 : cmask[(size_t)b * C_LEN + (t - S_LEN)];
        }

        float p[4][4], tmax[4];
#pragma unroll
        for (int i = 0; i < 4; ++i) tmax[i] = -__builtin_inff();
#pragma unroll
        for (int nf = 0; nf < 4; ++nf)
#pragma unroll
            for (int i = 0; i < 4; ++i) {
                float z = sa[nf][i] * (mrow[i] * mc[nf]);
                p[nf][i] = z;
                tmax[i] = fmaxf(tmax[i], z);
            }
#pragma unroll
        for (int m = 1; m <= 8; m <<= 1)
#pragma unroll
            for (int i = 0; i < 4; ++i)
                tmax[i] = fmaxf(tmax[i], __shfl_xor(tmax[i], m));

        float al[4], rs[4];
#pragma unroll
        for (int i = 0; i < 4; ++i) {
            float mn = fmaxf(mM[i], tmax[i]);
            al[i] = __expf(mM[i] - mn);
            mM[i] = mn;
            rs[i] = 0.f;
        }
#pragma unroll
        for (int nf = 0; nf < 4; ++nf)
#pragma unroll
            for (int i = 0; i < 4; ++i) {
                float e = __expf(p[nf][i] - mM[i]) * (mrow[i] * mc[nf]);
                p[nf][i] = e;
                rs[i] += e;
            }
#pragma unroll
        for (int m = 1; m <= 8; m <<= 1)
#pragma unroll
            for (int i = 0; i < 4; ++i)
                rs[i] += __shfl_xor(rs[i], m);
#pragma unroll
        for (int i = 0; i < 4; ++i) lS[i] = lS[i] * al[i] + rs[i];
#pragma unroll
        for (int df = 0; df < 4; ++df)
#pragma unroll
            for (int i = 0; i < 4; ++i) accO[df][i] *= al[i];

        // P -> per-wave LDS (reshape C-layout -> A-fragment layout)
#pragma unroll
        for (int nf = 0; nf < 4; ++nf)
#pragma unroll
            for (int i = 0; i < 4; ++i)
                Ps[w][lg * 4 + i][nf * 16 + l15] = f2bf(p[nf][i]);

        bf16x8 pf0 = *(const bf16x8*)&Ps[w][l15][lg * 8];
        bf16x8 pf1 = *(const bf16x8*)&Ps[w][l15][lg * 8 + 32];
#pragma unroll
        for (int df = 0; df < 4; ++df) {
            bf16x8 vf0 = *(const bf16x8*)&Vs[df * 16 + l15][lg * 8];
            bf16x8 vf1 = *(const bf16x8*)&Vs[df * 16 + l15][lg * 8 + 32];
            accO[df] = __builtin_amdgcn_mfma_f32_16x16x32_bf16(pf0, vf0, accO[df], 0, 0, 0);
            accO[df] = __builtin_amdgcn_mfma_f32_16x16x32_bf16(pf1, vf1, accO[df], 0, 0, 0);
        }
        __syncthreads();
    }

    float inv[4];
#pragma unroll
    for (int i = 0; i < 4; ++i) inv[i] = 1.f / (lS[i] + 1e-13f);
#pragma unroll
    for (int df = 0; df < 4; ++df)
#pragma unroll
        for (int i = 0; i < 4; ++i) {
            size_t srow = (size_t)b * S_LEN + qrow + lg * 4 + i;
            O[srow * EMB_ + h * 64 + df * 16 + l15] = f2bf(accO[df][i] * inv[i]);
        }
}

// ------------------------------------------------------------------ launch
extern "C" void kernel_launch(void* const* d_in, const int* in_sizes, int n_in,
                              void* d_out, int out_size, void* d_ws, size_t ws_size,
                              hipStream_t stream) {
    const float* x     = (const float*)d_in[0];
    const float* ctx   = (const float*)d_in[1];
    const float* mask  = (const float*)d_in[2];
    const float* cmask = (const float*)d_in[3];
    const float* Wq    = (const float*)d_in[4];
    const float* Wk    = (const float*)d_in[5];
    const float* Wv    = (const float*)d_in[6];
    const float* Wu    = (const float*)d_in[7];
    const float* bu    = (const float*)d_in[8];
    const float* qlnw  = (const float*)d_in[9];
    const float* qlnb  = (const float*)d_in[10];
    const float* klnw  = (const float*)d_in[11];
    const float* klnb  = (const float*)d_in[12];

    unsigned short* ws = (unsigned short*)d_ws;
    // region 0 (25.17MB): xcb + WqT/WkT/WvT during GEMMs; reused for Q + K after
    unsigned short* xcb = ws + 0;               //  8,388,608 elems
    unsigned short* WqT = ws + 8388608;         //  1,048,576
    unsigned short* WkT = ws + 9437184;
    unsigned short* WvT = ws + 10485760;
    unsigned short* Qb  = ws + 0;               //  4,194,304 (over dead xcb)
    unsigned short* Kb  = ws + 4194304;         //  8,388,608 (over dead xcb/W*T)
    unsigned short* WuT = ws + 12582912;        //  1,048,576 (lives to the end)
    unsigned short* Yq  = ws + 13631488;        //  4,194,304 ; reused as O
    unsigned short* Ob  = Yq;
    unsigned short* Yk  = ws + 17825792;        //  8,388,608 ; reused as VT
    unsigned short* VTb = Yk;
    unsigned short* Yv  = ws + 26214400;        //  8,388,608
    // total: 34,603,008 elems = 69,206,016 bytes

    const float scale = 0.17677669529663687f;   // 1024^-0.25

    build_xcb_k<<<4096, 256, 0, stream>>>(x, ctx, xcb);
    dim3 wt(16, 16);
    wtrans_k<<<wt, 256, 0, stream>>>(Wq, WqT);
    wtrans_k<<<wt, 256, 0, stream>>>(Wk, WkT);
    wtrans_k<<<wt, 256, 0, stream>>>(Wv, WvT);
    wtrans_k<<<wt, 256, 0, stream>>>(Wu, WuT);

    gemm_bt_k<false><<<dim3(8, 64), 256, 0, stream>>>(xcb, WkT, Yk, nullptr, 64, 8192);
    gemm_bt_k<false><<<dim3(8, 64), 256, 0, stream>>>(xcb, WvT, Yv, nullptr, 64, 8192);
    gemm_bt_k<false><<<dim3(8, 32), 256, 0, stream>>>(xcb, WqT, Yq, nullptr, 16, 4096);

    ln_head_k<<<16384, 256, 0, stream>>>(Yq, Qb, qlnw, qlnb, S_LEN, scale);
    ln_head_k<<<32768, 256, 0, stream>>>(Yk, Kb, klnw, klnb, T_LEN, scale);
    vtrans_k<<<dim3(64, 32), 256, 0, stream>>>(Yv, VTb);

    attn_k<<<dim3(32, 32), 256, 0, stream>>>(Qb, Kb, VTb, mask, cmask, Ob);

    gemm_bt_k<true><<<dim3(8, 32), 256, 0, stream>>>(Ob, WuT, d_out, bu, 32, 4096);
}

// Round 2
// 366.096 us; speedup vs baseline: 1.1316x; 1.1316x over previous
//
#include <hip/hip_runtime.h>
#include <hip/hip_bf16.h>
#include <cstdint>

#define B_SZ   2
#define S_LEN  2048
#define C_LEN  2048
#define T_LEN  4096
#define EMB_   1024
#define HEADS_ 16
#define D_     64

typedef __attribute__((ext_vector_type(8))) short bf16x8;
typedef __attribute__((ext_vector_type(4))) float f32x4;
typedef __attribute__((ext_vector_type(16))) float f32x16;
typedef unsigned short ushort_t;

__device__ __forceinline__ unsigned short f2bf(float f) {
    unsigned u = __builtin_bit_cast(unsigned, f);
    u += 0x7fffu + ((u >> 16) & 1u);
    return (unsigned short)(u >> 16);
}
__device__ __forceinline__ float bf2f(unsigned short h) {
    return __builtin_bit_cast(float, (unsigned)h << 16);
}

// ---------------------------------------------------------------- xcb build
__global__ void build_xcb_k(const float* __restrict__ x, const float* __restrict__ ctx,
                            unsigned short* __restrict__ xcb) {
    int i = blockIdx.x * blockDim.x + threadIdx.x;      // one 8-elem chunk
    size_t e8 = (size_t)i * 8;
    int b = (int)(e8 / ((size_t)T_LEN * EMB_));
    size_t rem = e8 % ((size_t)T_LEN * EMB_);
    int t = (int)(rem / EMB_);
    int c = (int)(rem % EMB_);
    const float* src = (t < S_LEN)
        ? &x[((size_t)b * S_LEN + t) * EMB_ + c]
        : &ctx[((size_t)b * C_LEN + (t - S_LEN)) * EMB_ + c];
    float4 v0 = ((const float4*)src)[0];
    float4 v1 = ((const float4*)src)[1];
    uint4 o;
    o.x = (unsigned)f2bf(v0.x) | ((unsigned)f2bf(v0.y) << 16);
    o.y = (unsigned)f2bf(v0.z) | ((unsigned)f2bf(v0.w) << 16);
    o.z = (unsigned)f2bf(v1.x) | ((unsigned)f2bf(v1.y) << 16);
    o.w = (unsigned)f2bf(v1.z) | ((unsigned)f2bf(v1.w) << 16);
    *(uint4*)&xcb[e8] = o;
}

// ------------------------------------------------- weight transpose+convert
__global__ void wtrans_k(const float* __restrict__ W, unsigned short* __restrict__ WT) {
    __shared__ __align__(16) unsigned short tile[64][72];
    int bx = blockIdx.x, by = blockIdx.y;   // bx: n-tile, by: k-tile
    int tid = threadIdx.x;
#pragma unroll
    for (int r = 0; r < 4; ++r) {
        int idx = tid + r * 256;
        int row = idx >> 4, c4 = idx & 15;
        float4 v = ((const float4*)&W[((size_t)(by * 64 + row)) * EMB_ + bx * 64])[c4];
        tile[row][c4 * 4 + 0] = f2bf(v.x);
        tile[row][c4 * 4 + 1] = f2bf(v.y);
        tile[row][c4 * 4 + 2] = f2bf(v.z);
        tile[row][c4 * 4 + 3] = f2bf(v.w);
    }
    __syncthreads();
#pragma unroll
    for (int r = 0; r < 2; ++r) {
        int idx = tid + r * 256;
        int n = idx >> 3, k8 = idx & 7;
        uint4 o;
        unsigned q[4];
#pragma unroll
        for (int j = 0; j < 4; ++j)
            q[j] = (unsigned)tile[k8 * 8 + 2 * j][n] | ((unsigned)tile[k8 * 8 + 2 * j + 1][n] << 16);
        o.x = q[0]; o.y = q[1]; o.z = q[2]; o.w = q[3];
        *(uint4*)&WT[((size_t)(bx * 64 + n)) * EMB_ + by * 64 + k8 * 8] = o;
    }
}

// ---------------------------------------------------------------- GEMM (m97-style)
template <bool F32OUT>
__global__ __launch_bounds__(256) void gemm_bt_k(
    const unsigned short* __restrict__ A,
    const unsigned short* __restrict__ Bt,
    void* __restrict__ Cout,
    const float* __restrict__ bias,
    int mtiles_per_chunk, int chunk_stride) {
    constexpr int KTOT = 1024, NTOT = 1024;
    __shared__ __align__(16) unsigned short As[128 * 32];
    __shared__ __align__(16) unsigned short Bs[128 * 32];
    int nt = blockIdx.x, mt = blockIdx.y;
    int in_row0 = (mt / mtiles_per_chunk) * chunk_stride + (mt % mtiles_per_chunk) * 128;
    int out_row0 = mt * 128;
    int tid = threadIdx.x, w = tid >> 6, l = tid & 63, l15 = l & 15, lg = l >> 4;
    int wr = (w >> 1) * 64, wc = (w & 1) * 64;

    f32x4 zero4 = {0.f, 0.f, 0.f, 0.f};
    f32x4 acc[4][4];
#pragma unroll
    for (int i = 0; i < 4; ++i)
#pragma unroll
        for (int j = 0; j < 4; ++j) acc[i][j] = zero4;

    for (int k0 = 0; k0 < KTOT; k0 += 32) {
#pragma unroll
        for (int j = 0; j < 2; ++j) {
            int o = tid * 16 + j * 4096;        // byte offset in 8KB tile
            int row = o >> 6;                   // 64B per row (32 bf16)
            int ke = (o & 63) >> 1;             // element offset in row
            __builtin_amdgcn_global_load_lds(
                (const __attribute__((address_space(1))) void*)&A[(size_t)(in_row0 + row) * KTOT + k0 + ke],
                (__attribute__((address_space(3))) void*)&As[o >> 1], 16, 0, 0);
            __builtin_amdgcn_global_load_lds(
                (const __attribute__((address_space(1))) void*)&Bt[(size_t)(nt * 128 + row) * KTOT + k0 + ke],
                (__attribute__((address_space(3))) void*)&Bs[o >> 1], 16, 0, 0);
        }
        __syncthreads();
        bf16x8 af[4], bf[4];
#pragma unroll
        for (int fr = 0; fr < 4; ++fr)
            af[fr] = *(const bf16x8*)&As[(wr + fr * 16 + l15) * 32 + lg * 8];
#pragma unroll
        for (int fc = 0; fc < 4; ++fc)
            bf[fc] = *(const bf16x8*)&Bs[(wc + fc * 16 + l15) * 32 + lg * 8];
#pragma unroll
        for (int fr = 0; fr < 4; ++fr)
#pragma unroll
            for (int fc = 0; fc < 4; ++fc)
                acc[fr][fc] = __builtin_amdgcn_mfma_f32_16x16x32_bf16(af[fr], bf[fc], acc[fr][fc], 0, 0, 0);
        __syncthreads();
    }
#pragma unroll
    for (int fr = 0; fr < 4; ++fr) {
#pragma unroll
        for (int fc = 0; fc < 4; ++fc) {
            int row = out_row0 + wr + fr * 16 + lg * 4;
            int col = nt * 128 + wc + fc * 16 + l15;
#pragma unroll
            for (int i = 0; i < 4; ++i) {
                float v = acc[fr][fc][i];
                if (F32OUT) {
                    ((float*)Cout)[(size_t)(row + i) * NTOT + col] = v + bias[col];
                } else {
                    ((unsigned short*)Cout)[(size_t)(row + i) * NTOT + col] = f2bf(v);
                }
            }
        }
    }
}

// -------------------------------------------------- per-head LayerNorm (+scale)
__global__ void ln_head_k(const unsigned short* __restrict__ Y,
                          unsigned short* __restrict__ Out,
                          const float* __restrict__ lw, const float* __restrict__ lb,
                          int rows_per_b, float scale) {
    int gw = blockIdx.x * 4 + (threadIdx.x >> 6);
    int lane = threadIdx.x & 63;
    int h = gw % HEADS_;
    int row = gw / HEADS_;                   // [0, B*rows_per_b)
    int b = row / rows_per_b, r = row % rows_per_b;
    float v = bf2f(Y[(size_t)row * EMB_ + h * 64 + lane]);
    float s = v, s2 = v * v;
#pragma unroll
    for (int m = 1; m <= 32; m <<= 1) {
        s += __shfl_xor(s, m);
        s2 += __shfl_xor(s2, m);
    }
    float mu = s * (1.f / 64.f);
    float var = s2 * (1.f / 64.f) - mu * mu;
    float o = (v - mu) * rsqrtf(var + 1e-5f) * lw[lane] + lb[lane];
    Out[(((size_t)b * HEADS_ + h) * rows_per_b + r) * 64 + lane] = f2bf(o * scale);
}

// ---------------------------------------------------- V transpose [B,H,D,T]
__global__ void vtrans_k(const unsigned short* __restrict__ Yv, unsigned short* __restrict__ VT) {
    __shared__ __align__(16) unsigned short tile[64][72];
    int t0 = blockIdx.x * 64;
    int bh = blockIdx.y;
    int b = bh >> 4, h = bh & 15;
    int tid = threadIdx.x;
#pragma unroll
    for (int r = 0; r < 2; ++r) {
        int idx = tid + r * 256;
        int row = idx >> 3, c8 = idx & 7;
        uint4 v = *(const uint4*)&Yv[((size_t)b * T_LEN + t0 + row) * EMB_ + h * 64 + c8 * 8];
        *(uint4*)&tile[row][c8 * 8] = v;
    }
    __syncthreads();
#pragma unroll
    for (int r = 0; r < 2; ++r) {
        int idx = tid + r * 256;
        int d = idx >> 3, t8 = idx & 7;
        uint4 o;
        unsigned q[4];
#pragma unroll
        for (int j = 0; j < 4; ++j)
            q[j] = (unsigned)tile[t8 * 8 + 2 * j][d] | ((unsigned)tile[t8 * 8 + 2 * j + 1][d] << 16);
        o.x = q[0]; o.y = q[1]; o.z = q[2]; o.w = q[3];
        *(uint4*)&VT[((size_t)bh * 64 + d) * T_LEN + t0 + t8 * 8] = o;
    }
}

// ---------------------------------------------------------- flash attention
// 32x32x16 MFMA, no-LDS main loop, swapped QK^T, sigma-permuted PV, t-split waves.
// Q has been pre-scaled by log2(e) so exp uses raw v_exp_f32 (exp2).
#define SOFTMAX(SA, MQ, MM, LS, ACA, ACB, PB0, PB1) do {                          \
    float z_[16]; float tm_ = -1e38f;                                            \
    _Pragma("unroll") for (int r_ = 0; r_ < 16; ++r_) {                          \
        float mp_ = mt_[r_] * (MQ);                                              \
        z_[r_] = SA[r_] * mp_;                                                   \
        tm_ = fmaxf(tm_, z_[r_]);                                                \
    }                                                                             \
    tm_ = fmaxf(tm_, __shfl_xor(tm_, 32));                                        \
    if (__any(tm_ > (MM))) {                                                      \
        float mn_ = fmaxf((MM), tm_);                                            \
        float al_ = __builtin_amdgcn_exp2f((MM) - mn_);                          \
        (MM) = mn_; (LS) *= al_; (ACA) *= al_; (ACB) *= al_;                      \
    }                                                                             \
    float rs_ = 0.f;                                                              \
    _Pragma("unroll") for (int r_ = 0; r_ < 16; ++r_) {                          \
        z_[r_] = __builtin_amdgcn_exp2f(z_[r_] - (MM)) * (mt_[r_] * (MQ));        \
        rs_ += z_[r_];                                                            \
    }                                                                             \
    rs_ += __shfl_xor(rs_, 32); (LS) += rs_;                                      \
    unsigned pk_[8];                                                              \
    _Pragma("unroll") for (int d_ = 0; d_ < 8; ++d_)                              \
        asm("v_cvt_pk_bf16_f32 %0, %1, %2" : "=v"(pk_[d_])                        \
            : "v"(z_[2*d_]), "v"(z_[2*d_+1]));                                    \
    { uint4 u0_; u0_.x=pk_[0]; u0_.y=pk_[1]; u0_.z=pk_[2]; u0_.w=pk_[3];          \
      uint4 u1_; u1_.x=pk_[4]; u1_.y=pk_[5]; u1_.z=pk_[6]; u1_.w=pk_[7];          \
      (PB0) = __builtin_bit_cast(bf16x8, u0_);                                    \
      (PB1) = __builtin_bit_cast(bf16x8, u1_); }                                  \
} while (0)

#define LOADK(DST, KT) do {                                                       \
    size_t o_ = (size_t)(KT) * 2048;                                              \
    _Pragma("unroll") for (int s_ = 0; s_ < 4; ++s_)                              \
        DST[s_] = *(const uint4*)(Kl + o_ + s_ * 16);                             \
} while (0)

#define VMAKE(LO, HI) __builtin_bit_cast(bf16x8, (uint4){(LO).x, (LO).y, (HI).x, (HI).y})

__global__ __launch_bounds__(256) void attn32_k(
    const unsigned short* __restrict__ Q,    // [B,H,S,64], pre-scaled w/ log2e
    const unsigned short* __restrict__ K,    // [B,H,T,64]
    const unsigned short* __restrict__ VT,   // [B,H,64,T]
    const float* __restrict__ mask,          // [B,S]
    const float* __restrict__ cmask,         // [B,C]
    unsigned short* __restrict__ O) {        // [B,S,EMB]
    __shared__ float Olds[4][32][64];
    __shared__ float Mlds[4][64];
    __shared__ float Llds[4][64];

    int qblk = blockIdx.x, bh = blockIdx.y;
    int b = bh >> 4, h = bh & 15;
    int tid = threadIdx.x;
    int w = tid >> 6;
    int lane = tid & 63;
    int l31 = lane & 31;
    int hi = lane >> 5;
    int q0 = qblk * 64;

    const unsigned short* Kp = K + (size_t)bh * T_LEN * 64;
    const unsigned short* Vp = VT + (size_t)bh * 64 * T_LEN;
    const unsigned short* Kl = Kp + (size_t)l31 * 64 + hi * 8;

    // Q fragments (held for whole kernel)
    bf16x8 qf0[4], qf1[4];
    {
        const unsigned short* Qp0 = Q + ((size_t)bh * S_LEN + q0 + l31) * 64 + hi * 8;
        const unsigned short* Qp1 = Qp0 + (size_t)32 * 64;
#pragma unroll
        for (int s = 0; s < 4; ++s) {
            qf0[s] = *(const bf16x8*)(Qp0 + s * 16);
            qf1[s] = *(const bf16x8*)(Qp1 + s * 16);
        }
    }
    float mq0 = mask[(size_t)b * S_LEN + q0 + l31];
    float mq1 = mask[(size_t)b * S_LEN + q0 + 32 + l31];

    f32x16 Z16;
#pragma unroll
    for (int i = 0; i < 16; ++i) Z16[i] = 0.f;
    f32x16 acc00 = Z16, acc01 = Z16, acc10 = Z16, acc11 = Z16;  // acc[db][qb]
    float mM0 = -1e38f, mM1 = -1e38f, lS0 = 0.f, lS1 = 0.f;

    auto TILE = [&](const uint4* kf, int kt) {
        const int t0 = kt * 32;
        // --- V loads (needed only after softmax; latency hides under QK) ---
        const unsigned short* Vl = Vp + (size_t)l31 * T_LEN + t0 + 4 * hi;
        const unsigned short* Vl1 = Vl + (size_t)32 * T_LEN;
        uint2 v00a = *(const uint2*)(Vl);
        uint2 v00b = *(const uint2*)(Vl + 8);
        uint2 v01a = *(const uint2*)(Vl + 16);
        uint2 v01b = *(const uint2*)(Vl + 24);
        uint2 v10a = *(const uint2*)(Vl1);
        uint2 v10b = *(const uint2*)(Vl1 + 8);
        uint2 v11a = *(const uint2*)(Vl1 + 16);
        uint2 v11b = *(const uint2*)(Vl1 + 24);
        // --- t-mask loads (tile is entirely within one mask region) ---
        const float* mbase = (t0 < S_LEN)
            ? (mask + (size_t)b * S_LEN + t0)
            : (cmask + (size_t)b * C_LEN + (t0 - S_LEN));
        float4 mf0 = *(const float4*)(mbase + 4 * hi);
        float4 mf1 = *(const float4*)(mbase + 8 + 4 * hi);
        float4 mf2 = *(const float4*)(mbase + 16 + 4 * hi);
        float4 mf3 = *(const float4*)(mbase + 24 + 4 * hi);
        // --- S^T = K · Q^T ---
        f32x16 sa0 = Z16, sa1 = Z16;
#pragma unroll
        for (int s = 0; s < 4; ++s) {
            bf16x8 kfr = __builtin_bit_cast(bf16x8, kf[s]);
            sa0 = __builtin_amdgcn_mfma_f32_32x32x16_bf16(kfr, qf0[s], sa0, 0, 0, 0);
            sa1 = __builtin_amdgcn_mfma_f32_32x32x16_bf16(kfr, qf1[s], sa1, 0, 0, 0);
        }
        float mt_[16];
        mt_[0] = mf0.x; mt_[1] = mf0.y; mt_[2]  = mf0.z; mt_[3]  = mf0.w;
        mt_[4] = mf1.x; mt_[5] = mf1.y; mt_[6]  = mf1.z; mt_[7]  = mf1.w;
        mt_[8] = mf2.x; mt_[9] = mf2.y; mt_[10] = mf2.z; mt_[11] = mf2.w;
        mt_[12] = mf3.x; mt_[13] = mf3.y; mt_[14] = mf3.z; mt_[15] = mf3.w;
        // --- online softmax (lane-local, one shuffle per reduction) ---
        bf16x8 p00, p01, p10, p11;
        SOFTMAX(sa0, mq0, mM0, lS0, acc00, acc10, p00, p01);
        SOFTMAX(sa1, mq1, mM1, lS1, acc01, acc11, p10, p11);
        // --- O^T += V^T · P^T (sigma-permuted k so P frags are lane-local) ---
        bf16x8 vf;
        vf = VMAKE(v00a, v00b);
        acc00 = __builtin_amdgcn_mfma_f32_32x32x16_bf16(vf, p00, acc00, 0, 0, 0);
        acc01 = __builtin_amdgcn_mfma_f32_32x32x16_bf16(vf, p10, acc01, 0, 0, 0);
        vf = VMAKE(v01a, v01b);
        acc00 = __builtin_amdgcn_mfma_f32_32x32x16_bf16(vf, p01, acc00, 0, 0, 0);
        acc01 = __builtin_amdgcn_mfma_f32_32x32x16_bf16(vf, p11, acc01, 0, 0, 0);
        vf = VMAKE(v10a, v10b);
        acc10 = __builtin_amdgcn_mfma_f32_32x32x16_bf16(vf, p00, acc10, 0, 0, 0);
        acc11 = __builtin_amdgcn_mfma_f32_32x32x16_bf16(vf, p10, acc11, 0, 0, 0);
        vf = VMAKE(v11a, v11b);
        acc10 = __builtin_amdgcn_mfma_f32_32x32x16_bf16(vf, p01, acc10, 0, 0, 0);
        acc11 = __builtin_amdgcn_mfma_f32_32x32x16_bf16(vf, p11, acc11, 0, 0, 0);
    };

    // --- main t-loop: wave w owns tiles kt = w, w+4, ..., w+124 (no barriers) ---
    uint4 ka[4], kb[4];
    LOADK(ka, w);
    for (int it = 0; it < 32; it += 2) {
        int kt0 = w + it * 4;
        LOADK(kb, kt0 + 4);
        TILE(ka, kt0);
        LOADK(ka, (it + 2 < 32) ? kt0 + 8 : kt0);
        TILE(kb, kt0 + 4);
    }

    // --- merge 4 waves' partial (m, l, O^T) via LDS, two d-halves ---
    if (hi == 0) {
        Mlds[w][l31] = mM0;      Llds[w][l31] = lS0;
        Mlds[w][32 + l31] = mM1; Llds[w][32 + l31] = lS1;
    }
    int qm = tid & 63;
    float f0, f1, f2, f3, invL;

    // pass 0: db = 0
#pragma unroll
    for (int r = 0; r < 16; ++r) {
        int dl = (r & 3) + 8 * (r >> 2) + 4 * hi;
        Olds[w][dl][l31] = acc00[r];
        Olds[w][dl][32 + l31] = acc01[r];
    }
    __syncthreads();
    {
        float m0_ = Mlds[0][qm], m1_ = Mlds[1][qm], m2_ = Mlds[2][qm], m3_ = Mlds[3][qm];
        float Mx = fmaxf(fmaxf(m0_, m1_), fmaxf(m2_, m3_));
        f0 = __builtin_amdgcn_exp2f(m0_ - Mx);
        f1 = __builtin_amdgcn_exp2f(m1_ - Mx);
        f2 = __builtin_amdgcn_exp2f(m2_ - Mx);
        f3 = __builtin_amdgcn_exp2f(m3_ - Mx);
        float L = Llds[0][qm] * f0 + Llds[1][qm] * f1 + Llds[2][qm] * f2 + Llds[3][qm] * f3;
        invL = 1.f / (L + 1e-13f);
    }
    {
        float v_[8];
#pragma unroll
        for (int dd = 0; dd < 8; ++dd) {
            int d = w * 8 + dd;
            v_[dd] = (Olds[0][d][qm] * f0 + Olds[1][d][qm] * f1 +
                      Olds[2][d][qm] * f2 + Olds[3][d][qm] * f3) * invL;
        }
        unsigned po_[4];
#pragma unroll
        for (int d2 = 0; d2 < 4; ++d2)
            asm("v_cvt_pk_bf16_f32 %0, %1, %2" : "=v"(po_[d2]) : "v"(v_[2*d2]), "v"(v_[2*d2+1]));
        uint4 st; st.x = po_[0]; st.y = po_[1]; st.z = po_[2]; st.w = po_[3];
        *(uint4*)&O[((size_t)b * S_LEN + q0 + qm) * EMB_ + h * 64 + w * 8] = st;
    }
    __syncthreads();
    // pass 1: db = 1
#pragma unroll
    for (int r = 0; r < 16; ++r) {
        int dl = (r & 3) + 8 * (r >> 2) + 4 * hi;
        Olds[w][dl][l31] = acc10[r];
        Olds[w][dl][32 + l31] = acc11[r];
    }
    __syncthreads();
    {
        float v_[8];
#pragma unroll
        for (int dd = 0; dd < 8; ++dd) {
            int d = w * 8 + dd;
            v_[dd] = (Olds[0][d][qm] * f0 + Olds[1][d][qm] * f1 +
                      Olds[2][d][qm] * f2 + Olds[3][d][qm] * f3) * invL;
        }
        unsigned po_[4];
#pragma unroll
        for (int d2 = 0; d2 < 4; ++d2)
            asm("v_cvt_pk_bf16_f32 %0, %1, %2" : "=v"(po_[d2]) : "v"(v_[2*d2]), "v"(v_[2*d2+1]));
        uint4 st; st.x = po_[0]; st.y = po_[1]; st.z = po_[2]; st.w = po_[3];
        *(uint4*)&O[((size_t)b * S_LEN + q0 + qm) * EMB_ + h * 64 + 32 + w * 8] = st;
    }
}

// ------------------------------------------------------------------ launch
extern "C" void kernel_launch(void* const* d_in, const int* in_sizes, int n_in,
                              void* d_out, int out_size, void* d_ws, size_t ws_size,
                              hipStream_t stream) {
    const float* x     = (const float*)d_in[0];
    const float* ctx   = (const float*)d_in[1];
    const float* mask  = (const float*)d_in[2];
    const float* cmask = (const float*)d_in[3];
    const float* Wq    = (const float*)d_in[4];
    const float* Wk    = (const float*)d_in[5];
    const float* Wv    = (const float*)d_in[6];
    const float* Wu    = (const float*)d_in[7];
    const float* bu    = (const float*)d_in[8];
    const float* qlnw  = (const float*)d_in[9];
    const float* qlnb  = (const float*)d_in[10];
    const float* klnw  = (const float*)d_in[11];
    const float* klnb  = (const float*)d_in[12];

    unsigned short* ws = (unsigned short*)d_ws;
    unsigned short* xcb = ws + 0;               //  8,388,608 elems
    unsigned short* WqT = ws + 8388608;         //  1,048,576
    unsigned short* WkT = ws + 9437184;
    unsigned short* WvT = ws + 10485760;
    unsigned short* Qb  = ws + 0;               //  4,194,304 (over dead xcb)
    unsigned short* Kb  = ws + 4194304;         //  8,388,608 (over dead xcb/W*T)
    unsigned short* WuT = ws + 12582912;        //  1,048,576 (lives to the end)
    unsigned short* Yq  = ws + 13631488;        //  4,194,304 ; reused as O
    unsigned short* Ob  = Yq;
    unsigned short* Yk  = ws + 17825792;        //  8,388,608 ; reused as VT
    unsigned short* VTb = Yk;
    unsigned short* Yv  = ws + 26214400;        //  8,388,608

    const float scale = 0.17677669529663687f;               // 1024^-0.25
    const float qscale = 0.17677669529663687f * 1.4426950408889634f; // * log2(e)

    build_xcb_k<<<4096, 256, 0, stream>>>(x, ctx, xcb);
    dim3 wt(16, 16);
    wtrans_k<<<wt, 256, 0, stream>>>(Wq, WqT);
    wtrans_k<<<wt, 256, 0, stream>>>(Wk, WkT);
    wtrans_k<<<wt, 256, 0, stream>>>(Wv, WvT);
    wtrans_k<<<wt, 256, 0, stream>>>(Wu, WuT);

    gemm_bt_k<false><<<dim3(8, 64), 256, 0, stream>>>(xcb, WkT, Yk, nullptr, 64, 8192);
    gemm_bt_k<false><<<dim3(8, 64), 256, 0, stream>>>(xcb, WvT, Yv, nullptr, 64, 8192);
    gemm_bt_k<false><<<dim3(8, 32), 256, 0, stream>>>(xcb, WqT, Yq, nullptr, 16, 4096);

    ln_head_k<<<16384, 256, 0, stream>>>(Yq, Qb, qlnw, qlnb, S_LEN, qscale);
    ln_head_k<<<32768, 256, 0, stream>>>(Yk, Kb, klnw, klnb, T_LEN, scale);
    vtrans_k<<<dim3(64, 32), 256, 0, stream>>>(Yv, VTb);

    attn32_k<<<dim3(32, 32), 256, 0, stream>>>(Qb, Kb, VTb, mask, cmask, Ob);

    gemm_bt_k<true><<<dim3(8, 32), 256, 0, stream>>>(Ob, WuT, d_out, bu, 32, 4096);
}

// Round 3
// 328.647 us; speedup vs baseline: 1.2606x; 1.1140x over previous
//
#include <hip/hip_runtime.h>
#include <hip/hip_bf16.h>
#include <cstdint>

#define B_SZ   2
#define S_LEN  2048
#define C_LEN  2048
#define T_LEN  4096
#define EMB_   1024
#define HEADS_ 16
#define D_     64

typedef __attribute__((ext_vector_type(8))) short bf16x8;
typedef __attribute__((ext_vector_type(4))) float f32x4;
typedef __attribute__((ext_vector_type(16))) float f32x16;

__device__ __forceinline__ unsigned short f2bf(float f) {
    unsigned u = __builtin_bit_cast(unsigned, f);
    u += 0x7fffu + ((u >> 16) & 1u);
    return (unsigned short)(u >> 16);
}
__device__ __forceinline__ float bf2f(unsigned short h) {
    return __builtin_bit_cast(float, (unsigned)h << 16);
}

// ---------------------------------------------------------------- xcb build
__global__ void build_xcb_k(const float* __restrict__ x, const float* __restrict__ ctx,
                            unsigned short* __restrict__ xcb) {
    int i = blockIdx.x * blockDim.x + threadIdx.x;      // one 8-elem chunk
    size_t e8 = (size_t)i * 8;
    int b = (int)(e8 / ((size_t)T_LEN * EMB_));
    size_t rem = e8 % ((size_t)T_LEN * EMB_);
    int t = (int)(rem / EMB_);
    int c = (int)(rem % EMB_);
    const float* src = (t < S_LEN)
        ? &x[((size_t)b * S_LEN + t) * EMB_ + c]
        : &ctx[((size_t)b * C_LEN + (t - S_LEN)) * EMB_ + c];
    float4 v0 = ((const float4*)src)[0];
    float4 v1 = ((const float4*)src)[1];
    uint4 o;
    o.x = (unsigned)f2bf(v0.x) | ((unsigned)f2bf(v0.y) << 16);
    o.y = (unsigned)f2bf(v0.z) | ((unsigned)f2bf(v0.w) << 16);
    o.z = (unsigned)f2bf(v1.x) | ((unsigned)f2bf(v1.y) << 16);
    o.w = (unsigned)f2bf(v1.z) | ((unsigned)f2bf(v1.w) << 16);
    *(uint4*)&xcb[e8] = o;
}

// --------------------------------------------------------------- mask concat
__global__ void mcat_k(const float* __restrict__ mask, const float* __restrict__ cmask,
                       float* __restrict__ Mcat) {
    int i = blockIdx.x * 256 + threadIdx.x;   // B*T total
    int b = i / T_LEN, t = i % T_LEN;
    Mcat[i] = (t < S_LEN) ? mask[(size_t)b * S_LEN + t]
                          : cmask[(size_t)b * C_LEN + (t - S_LEN)];
}

// ------------------------------------------------- weight transpose+convert
__global__ void wtrans_k(const float* __restrict__ W, unsigned short* __restrict__ WT) {
    __shared__ __align__(16) unsigned short tile[64][72];
    int bx = blockIdx.x, by = blockIdx.y;   // bx: n-tile, by: k-tile
    int tid = threadIdx.x;
#pragma unroll
    for (int r = 0; r < 4; ++r) {
        int idx = tid + r * 256;
        int row = idx >> 4, c4 = idx & 15;
        float4 v = ((const float4*)&W[((size_t)(by * 64 + row)) * EMB_ + bx * 64])[c4];
        tile[row][c4 * 4 + 0] = f2bf(v.x);
        tile[row][c4 * 4 + 1] = f2bf(v.y);
        tile[row][c4 * 4 + 2] = f2bf(v.z);
        tile[row][c4 * 4 + 3] = f2bf(v.w);
    }
    __syncthreads();
#pragma unroll
    for (int r = 0; r < 2; ++r) {
        int idx = tid + r * 256;
        int n = idx >> 3, k8 = idx & 7;
        uint4 o;
        unsigned q[4];
#pragma unroll
        for (int j = 0; j < 4; ++j)
            q[j] = (unsigned)tile[k8 * 8 + 2 * j][n] | ((unsigned)tile[k8 * 8 + 2 * j + 1][n] << 16);
        o.x = q[0]; o.y = q[1]; o.z = q[2]; o.w = q[3];
        *(uint4*)&WT[((size_t)(bx * 64 + n)) * EMB_ + by * 64 + k8 * 8] = o;
    }
}

// ---------------------------------------------------------------- GEMM (m97-style)
template <bool F32OUT>
__global__ __launch_bounds__(256) void gemm_bt_k(
    const unsigned short* __restrict__ A,
    const unsigned short* __restrict__ Bt,
    void* __restrict__ Cout,
    const float* __restrict__ bias,
    int mtiles_per_chunk, int chunk_stride) {
    constexpr int KTOT = 1024, NTOT = 1024;
    __shared__ __align__(16) unsigned short As[128 * 32];
    __shared__ __align__(16) unsigned short Bs[128 * 32];
    int nt = blockIdx.x, mt = blockIdx.y;
    int in_row0 = (mt / mtiles_per_chunk) * chunk_stride + (mt % mtiles_per_chunk) * 128;
    int out_row0 = mt * 128;
    int tid = threadIdx.x, w = tid >> 6, l = tid & 63, l15 = l & 15, lg = l >> 4;
    int wr = (w >> 1) * 64, wc = (w & 1) * 64;

    f32x4 zero4 = {0.f, 0.f, 0.f, 0.f};
    f32x4 acc[4][4];
#pragma unroll
    for (int i = 0; i < 4; ++i)
#pragma unroll
        for (int j = 0; j < 4; ++j) acc[i][j] = zero4;

    for (int k0 = 0; k0 < KTOT; k0 += 32) {
#pragma unroll
        for (int j = 0; j < 2; ++j) {
            int o = tid * 16 + j * 4096;        // byte offset in 8KB tile
            int row = o >> 6;                   // 64B per row (32 bf16)
            int ke = (o & 63) >> 1;             // element offset in row
            __builtin_amdgcn_global_load_lds(
                (const __attribute__((address_space(1))) void*)&A[(size_t)(in_row0 + row) * KTOT + k0 + ke],
                (__attribute__((address_space(3))) void*)&As[o >> 1], 16, 0, 0);
            __builtin_amdgcn_global_load_lds(
                (const __attribute__((address_space(1))) void*)&Bt[(size_t)(nt * 128 + row) * KTOT + k0 + ke],
                (__attribute__((address_space(3))) void*)&Bs[o >> 1], 16, 0, 0);
        }
        __syncthreads();
        bf16x8 af[4], bf[4];
#pragma unroll
        for (int fr = 0; fr < 4; ++fr)
            af[fr] = *(const bf16x8*)&As[(wr + fr * 16 + l15) * 32 + lg * 8];
#pragma unroll
        for (int fc = 0; fc < 4; ++fc)
            bf[fc] = *(const bf16x8*)&Bs[(wc + fc * 16 + l15) * 32 + lg * 8];
#pragma unroll
        for (int fr = 0; fr < 4; ++fr)
#pragma unroll
            for (int fc = 0; fc < 4; ++fc)
                acc[fr][fc] = __builtin_amdgcn_mfma_f32_16x16x32_bf16(af[fr], bf[fc], acc[fr][fc], 0, 0, 0);
        __syncthreads();
    }
#pragma unroll
    for (int fr = 0; fr < 4; ++fr) {
#pragma unroll
        for (int fc = 0; fc < 4; ++fc) {
            int row = out_row0 + wr + fr * 16 + lg * 4;
            int col = nt * 128 + wc + fc * 16 + l15;
#pragma unroll
            for (int i = 0; i < 4; ++i) {
                float v = acc[fr][fc][i];
                if (F32OUT) {
                    ((float*)Cout)[(size_t)(row + i) * NTOT + col] = v + bias[col];
                } else {
                    ((unsigned short*)Cout)[(size_t)(row + i) * NTOT + col] = f2bf(v);
                }
            }
        }
    }
}

// -------------------------------------------------- per-head LayerNorm (+scale)
__global__ void ln_head_k(const unsigned short* __restrict__ Y,
                          unsigned short* __restrict__ Out,
                          const float* __restrict__ lw, const float* __restrict__ lb,
                          int rows_per_b, float scale) {
    int gw = blockIdx.x * 4 + (threadIdx.x >> 6);
    int lane = threadIdx.x & 63;
    int h = gw % HEADS_;
    int row = gw / HEADS_;                   // [0, B*rows_per_b)
    int b = row / rows_per_b, r = row % rows_per_b;
    float v = bf2f(Y[(size_t)row * EMB_ + h * 64 + lane]);
    float s = v, s2 = v * v;
#pragma unroll
    for (int m = 1; m <= 32; m <<= 1) {
        s += __shfl_xor(s, m);
        s2 += __shfl_xor(s2, m);
    }
    float mu = s * (1.f / 64.f);
    float var = s2 * (1.f / 64.f) - mu * mu;
    float o = (v - mu) * rsqrtf(var + 1e-5f) * lw[lane] + lb[lane];
    Out[(((size_t)b * HEADS_ + h) * rows_per_b + r) * 64 + lane] = f2bf(o * scale);
}

// ------------------------- K LayerNorm + pack into MFMA-fragment order
// KF[bh][kt][s][l][j] = K[t=kt*32+(l&31)][d = s*16 + (l>>5)*8 + j]
__global__ void ln_head_pack_k(const unsigned short* __restrict__ Y,
                               unsigned short* __restrict__ KF,
                               const float* __restrict__ lw, const float* __restrict__ lb,
                               float scale) {
    int gw = blockIdx.x * 4 + (threadIdx.x >> 6);
    int lane = threadIdx.x & 63;
    int h = gw % HEADS_;
    int row = gw / HEADS_;                   // [0, B*T)
    int b = row / T_LEN, r = row % T_LEN;
    float v = bf2f(Y[(size_t)row * EMB_ + h * 64 + lane]);
    float s = v, s2 = v * v;
#pragma unroll
    for (int m = 1; m <= 32; m <<= 1) {
        s += __shfl_xor(s, m);
        s2 += __shfl_xor(s2, m);
    }
    float mu = s * (1.f / 64.f);
    float var = s2 * (1.f / 64.f) - mu * mu;
    float o = (v - mu) * rsqrtf(var + 1e-5f) * lw[lane] + lb[lane];
    int bh = b * HEADS_ + h;
    int kt = r >> 5, l31 = r & 31;
    int sf = lane >> 4, hi = (lane >> 3) & 1, j = lane & 7;
    size_t flat = ((((size_t)bh * 128 + kt) * 4 + sf) * 64 + hi * 32 + l31) * 8 + j;
    KF[flat] = f2bf(o * scale);
}

// ------------------------- V pack into MFMA-fragment order
// VF[bh][kt][f][l][j] = V^T[d][t]:
//   d = (f>>1)*32 + (l&31)
//   t = kt*32 + (f&1)*16 + (j>>2)*8 + 4*(l>>5) + (j&3)
__global__ void vpack_k(const unsigned short* __restrict__ Yv, unsigned short* __restrict__ VF) {
    __shared__ __align__(16) unsigned short tile[64][72];   // [t][d]
    int t0 = blockIdx.x * 64;      // 64 t-rows = 2 kt tiles
    int bh = blockIdx.y;
    int b = bh >> 4, h = bh & 15;
    int tid = threadIdx.x;
#pragma unroll
    for (int rr = 0; rr < 2; ++rr) {
        int idx = tid + rr * 256;
        int row = idx >> 3, c8 = idx & 7;
        *(uint4*)&tile[row][c8 * 8] =
            *(const uint4*)&Yv[((size_t)b * T_LEN + t0 + row) * EMB_ + h * 64 + c8 * 8];
    }
    __syncthreads();
    int f = tid >> 6, l = tid & 63;
    int d = (f >> 1) * 32 + (l & 31);
    int tb = (f & 1) * 16 + 4 * (l >> 5);
#pragma unroll
    for (int ktl = 0; ktl < 2; ++ktl) {
        unsigned short e[8];
#pragma unroll
        for (int j = 0; j < 8; ++j)
            e[j] = tile[ktl * 32 + tb + (j >> 2) * 8 + (j & 3)][d];
        uint4 o;
        o.x = (unsigned)e[0] | ((unsigned)e[1] << 16);
        o.y = (unsigned)e[2] | ((unsigned)e[3] << 16);
        o.z = (unsigned)e[4] | ((unsigned)e[5] << 16);
        o.w = (unsigned)e[6] | ((unsigned)e[7] << 16);
        size_t kt = (size_t)blockIdx.x * 2 + ktl;
        *(uint4*)&VF[((((size_t)bh * 128 + kt) * 4 + f) * 64 + l) * 8] = o;
    }
}

// ---------------------------------------------------------- flash attention
// 32x32x16 MFMA, zero-LDS main loop, swapped QK^T, sigma-permuted PV,
// fragment-packed K/V (coalesced 16B/lane loads), t-split waves.
// Q pre-scaled by log2(e) so exp uses raw v_exp_f32 (exp2).
#define SOFTMAX(SA, MQ, MM, LS, ACA, ACB, PB0, PB1) do {                          \
    float z_[16];                                                                 \
    _Pragma("unroll") for (int r_ = 0; r_ < 16; ++r_) {                          \
        float mp_ = mt_[r_] * (MQ);                                              \
        z_[r_] = SA[r_] * mp_;                                                   \
        SA[r_] = mp_;                                                            \
    }                                                                             \
    float ta_ = fmaxf(fmaxf(z_[0], z_[1]), z_[2]);                                \
    float tb_ = fmaxf(fmaxf(z_[3], z_[4]), z_[5]);                                \
    float tc_ = fmaxf(fmaxf(z_[6], z_[7]), z_[8]);                                \
    float td_ = fmaxf(fmaxf(z_[9], z_[10]), z_[11]);                              \
    float te_ = fmaxf(fmaxf(z_[12], z_[13]), z_[14]);                             \
    float tm_ = fmaxf(fmaxf(fmaxf(ta_, tb_), tc_),                                \
                      fmaxf(fmaxf(td_, te_), z_[15]));                            \
    tm_ = fmaxf(tm_, __shfl_xor(tm_, 32));                                        \
    if (__any(tm_ > (MM))) {                                                      \
        float mn_ = fmaxf((MM), tm_);                                            \
        float al_ = __builtin_amdgcn_exp2f((MM) - mn_);                          \
        (MM) = mn_; (LS) *= al_; (ACA) *= al_; (ACB) *= al_;                      \
    }                                                                             \
    float rsA_ = 0.f, rsB_ = 0.f;                                                 \
    _Pragma("unroll") for (int r_ = 0; r_ < 16; r_ += 2) {                        \
        z_[r_]     = __builtin_amdgcn_exp2f(z_[r_] - (MM)) * SA[r_];              \
        z_[r_ + 1] = __builtin_amdgcn_exp2f(z_[r_ + 1] - (MM)) * SA[r_ + 1];      \
        rsA_ += z_[r_]; rsB_ += z_[r_ + 1];                                       \
    }                                                                             \
    float rs_ = rsA_ + rsB_;                                                      \
    rs_ += __shfl_xor(rs_, 32); (LS) += rs_;                                      \
    unsigned pk_[8];                                                              \
    _Pragma("unroll") for (int d_ = 0; d_ < 8; ++d_)                              \
        asm("v_cvt_pk_bf16_f32 %0, %1, %2" : "=v"(pk_[d_])                        \
            : "v"(z_[2*d_]), "v"(z_[2*d_+1]));                                    \
    { uint4 u0_; u0_.x=pk_[0]; u0_.y=pk_[1]; u0_.z=pk_[2]; u0_.w=pk_[3];          \
      uint4 u1_; u1_.x=pk_[4]; u1_.y=pk_[5]; u1_.z=pk_[6]; u1_.w=pk_[7];          \
      (PB0) = __builtin_bit_cast(bf16x8, u0_);                                    \
      (PB1) = __builtin_bit_cast(bf16x8, u1_); }                                  \
} while (0)

#define LOADK(DST, KT) do {                                                       \
    const unsigned short* p_ = KFl + (size_t)(KT) * 2048;                         \
    DST[0] = *(const uint4*)(p_);                                                 \
    DST[1] = *(const uint4*)(p_ + 512);                                           \
    DST[2] = *(const uint4*)(p_ + 1024);                                          \
    DST[3] = *(const uint4*)(p_ + 1536);                                          \
} while (0)

__global__ __launch_bounds__(256) void attn32_k(
    const unsigned short* __restrict__ Q,    // [B,H,S,64], pre-scaled w/ log2e
    const unsigned short* __restrict__ KF,   // fragment-packed K
    const unsigned short* __restrict__ VF,   // fragment-packed V^T
    const float* __restrict__ Mcat,          // [B,T]
    unsigned short* __restrict__ O) {        // [B,S,EMB]
    __shared__ float Olds[4][32][64];
    __shared__ float Mlds[4][64];
    __shared__ float Llds[4][64];

    int qblk = blockIdx.x, bh = blockIdx.y;
    int b = bh >> 4, h = bh & 15;
    int tid = threadIdx.x;
    int w = tid >> 6;
    int lane = tid & 63;
    int l31 = lane & 31;
    int hi = lane >> 5;
    int q0 = qblk * 64;

    const unsigned short* KFl = KF + (size_t)bh * 262144 + lane * 8;
    const unsigned short* VFl = VF + (size_t)bh * 262144 + lane * 8;
    const float* Mb = Mcat + (size_t)b * T_LEN;

    // Q fragments (held for whole kernel)
    bf16x8 qf0[4], qf1[4];
    {
        const unsigned short* Qp0 = Q + ((size_t)bh * S_LEN + q0 + l31) * 64 + hi * 8;
        const unsigned short* Qp1 = Qp0 + (size_t)32 * 64;
#pragma unroll
        for (int s = 0; s < 4; ++s) {
            qf0[s] = *(const bf16x8*)(Qp0 + s * 16);
            qf1[s] = *(const bf16x8*)(Qp1 + s * 16);
        }
    }
    float mq0 = Mb[q0 + l31];          // q rows are in [0,S)
    float mq1 = Mb[q0 + 32 + l31];

    f32x16 Z16;
#pragma unroll
    for (int i = 0; i < 16; ++i) Z16[i] = 0.f;
    f32x16 acc00 = Z16, acc01 = Z16, acc10 = Z16, acc11 = Z16;  // acc[db][qb]
    float mM0 = -1e38f, mM1 = -1e38f, lS0 = 0.f, lS1 = 0.f;

    auto TILE = [&](const uint4* kf, int kt) {
        // --- V fragment loads (coalesced; latency hides under QK+softmax) ---
        const unsigned short* pv = VFl + (size_t)kt * 2048;
        uint4 vfr0 = *(const uint4*)(pv);
        uint4 vfr1 = *(const uint4*)(pv + 512);
        uint4 vfr2 = *(const uint4*)(pv + 1024);
        uint4 vfr3 = *(const uint4*)(pv + 1536);
        // --- t-mask loads ---
        const float* mbase = Mb + kt * 32;
        float4 mf0 = *(const float4*)(mbase + 4 * hi);
        float4 mf1 = *(const float4*)(mbase + 8 + 4 * hi);
        float4 mf2 = *(const float4*)(mbase + 16 + 4 * hi);
        float4 mf3 = *(const float4*)(mbase + 24 + 4 * hi);
        // --- S^T = K · Q^T ---
        f32x16 sa0 = Z16, sa1 = Z16;
#pragma unroll
        for (int s = 0; s < 4; ++s) {
            bf16x8 kfr = __builtin_bit_cast(bf16x8, kf[s]);
            sa0 = __builtin_amdgcn_mfma_f32_32x32x16_bf16(kfr, qf0[s], sa0, 0, 0, 0);
            sa1 = __builtin_amdgcn_mfma_f32_32x32x16_bf16(kfr, qf1[s], sa1, 0, 0, 0);
        }
        float mt_[16];
        mt_[0] = mf0.x; mt_[1] = mf0.y; mt_[2]  = mf0.z; mt_[3]  = mf0.w;
        mt_[4] = mf1.x; mt_[5] = mf1.y; mt_[6]  = mf1.z; mt_[7]  = mf1.w;
        mt_[8] = mf2.x; mt_[9] = mf2.y; mt_[10] = mf2.z; mt_[11] = mf2.w;
        mt_[12] = mf3.x; mt_[13] = mf3.y; mt_[14] = mf3.z; mt_[15] = mf3.w;
        // --- online softmax (lane-local, one shuffle per reduction) ---
        bf16x8 p00, p01, p10, p11;
        SOFTMAX(sa0, mq0, mM0, lS0, acc00, acc10, p00, p01);
        SOFTMAX(sa1, mq1, mM1, lS1, acc01, acc11, p10, p11);
        // --- O^T += V^T · P^T (sigma-permuted k so P frags are lane-local) ---
        bf16x8 vf;
        vf = __builtin_bit_cast(bf16x8, vfr0);
        acc00 = __builtin_amdgcn_mfma_f32_32x32x16_bf16(vf, p00, acc00, 0, 0, 0);
        acc01 = __builtin_amdgcn_mfma_f32_32x32x16_bf16(vf, p10, acc01, 0, 0, 0);
        vf = __builtin_bit_cast(bf16x8, vfr1);
        acc00 = __builtin_amdgcn_mfma_f32_32x32x16_bf16(vf, p01, acc00, 0, 0, 0);
        acc01 = __builtin_amdgcn_mfma_f32_32x32x16_bf16(vf, p11, acc01, 0, 0, 0);
        vf = __builtin_bit_cast(bf16x8, vfr2);
        acc10 = __builtin_amdgcn_mfma_f32_32x32x16_bf16(vf, p00, acc10, 0, 0, 0);
        acc11 = __builtin_amdgcn_mfma_f32_32x32x16_bf16(vf, p10, acc11, 0, 0, 0);
        vf = __builtin_bit_cast(bf16x8, vfr3);
        acc10 = __builtin_amdgcn_mfma_f32_32x32x16_bf16(vf, p01, acc10, 0, 0, 0);
        acc11 = __builtin_amdgcn_mfma_f32_32x32x16_bf16(vf, p11, acc11, 0, 0, 0);
    };

    // --- main t-loop: wave w owns tiles kt = w, w+4, ..., w+124 (no barriers) ---
    uint4 ka[4], kb[4];
    LOADK(ka, w);
    for (int it = 0; it < 32; it += 2) {
        int kt0 = w + it * 4;
        LOADK(kb, kt0 + 4);
        TILE(ka, kt0);
        LOADK(ka, (it + 2 < 32) ? kt0 + 8 : kt0);
        TILE(kb, kt0 + 4);
    }

    // --- merge 4 waves' partial (m, l, O^T) via LDS, two d-halves ---
    if (hi == 0) {
        Mlds[w][l31] = mM0;      Llds[w][l31] = lS0;
        Mlds[w][32 + l31] = mM1; Llds[w][32 + l31] = lS1;
    }
    int qm = tid & 63;
    float f0, f1, f2, f3, invL;

    // pass 0: db = 0
#pragma unroll
    for (int r = 0; r < 16; ++r) {
        int dl = (r & 3) + 8 * (r >> 2) + 4 * hi;
        Olds[w][dl][l31] = acc00[r];
        Olds[w][dl][32 + l31] = acc01[r];
    }
    __syncthreads();
    {
        float m0_ = Mlds[0][qm], m1_ = Mlds[1][qm], m2_ = Mlds[2][qm], m3_ = Mlds[3][qm];
        float Mx = fmaxf(fmaxf(m0_, m1_), fmaxf(m2_, m3_));
        f0 = __builtin_amdgcn_exp2f(m0_ - Mx);
        f1 = __builtin_amdgcn_exp2f(m1_ - Mx);
        f2 = __builtin_amdgcn_exp2f(m2_ - Mx);
        f3 = __builtin_amdgcn_exp2f(m3_ - Mx);
        float L = Llds[0][qm] * f0 + Llds[1][qm] * f1 + Llds[2][qm] * f2 + Llds[3][qm] * f3;
        invL = 1.f / (L + 1e-13f);
    }
    {
        float v_[8];
#pragma unroll
        for (int dd = 0; dd < 8; ++dd) {
            int d = w * 8 + dd;
            v_[dd] = (Olds[0][d][qm] * f0 + Olds[1][d][qm] * f1 +
                      Olds[2][d][qm] * f2 + Olds[3][d][qm] * f3) * invL;
        }
        unsigned po_[4];
#pragma unroll
        for (int d2 = 0; d2 < 4; ++d2)
            asm("v_cvt_pk_bf16_f32 %0, %1, %2" : "=v"(po_[d2]) : "v"(v_[2*d2]), "v"(v_[2*d2+1]));
        uint4 st; st.x = po_[0]; st.y = po_[1]; st.z = po_[2]; st.w = po_[3];
        *(uint4*)&O[((size_t)b * S_LEN + q0 + qm) * EMB_ + h * 64 + w * 8] = st;
    }
    __syncthreads();
    // pass 1: db = 1
#pragma unroll
    for (int r = 0; r < 16; ++r) {
        int dl = (r & 3) + 8 * (r >> 2) + 4 * hi;
        Olds[w][dl][l31] = acc10[r];
        Olds[w][dl][32 + l31] = acc11[r];
    }
    __syncthreads();
    {
        float v_[8];
#pragma unroll
        for (int dd = 0; dd < 8; ++dd) {
            int d = w * 8 + dd;
            v_[dd] = (Olds[0][d][qm] * f0 + Olds[1][d][qm] * f1 +
                      Olds[2][d][qm] * f2 + Olds[3][d][qm] * f3) * invL;
        }
        unsigned po_[4];
#pragma unroll
        for (int d2 = 0; d2 < 4; ++d2)
            asm("v_cvt_pk_bf16_f32 %0, %1, %2" : "=v"(po_[d2]) : "v"(v_[2*d2]), "v"(v_[2*d2+1]));
        uint4 st; st.x = po_[0]; st.y = po_[1]; st.z = po_[2]; st.w = po_[3];
        *(uint4*)&O[((size_t)b * S_LEN + q0 + qm) * EMB_ + h * 64 + 32 + w * 8] = st;
    }
}

// ------------------------------------------------------------------ launch
extern "C" void kernel_launch(void* const* d_in, const int* in_sizes, int n_in,
                              void* d_out, int out_size, void* d_ws, size_t ws_size,
                              hipStream_t stream) {
    const float* x     = (const float*)d_in[0];
    const float* ctx   = (const float*)d_in[1];
    const float* mask  = (const float*)d_in[2];
    const float* cmask = (const float*)d_in[3];
    const float* Wq    = (const float*)d_in[4];
    const float* Wk    = (const float*)d_in[5];
    const float* Wv    = (const float*)d_in[6];
    const float* Wu    = (const float*)d_in[7];
    const float* bu    = (const float*)d_in[8];
    const float* qlnw  = (const float*)d_in[9];
    const float* qlnb  = (const float*)d_in[10];
    const float* klnw  = (const float*)d_in[11];
    const float* klnb  = (const float*)d_in[12];

    unsigned short* ws = (unsigned short*)d_ws;
    unsigned short* xcb = ws + 0;               //  8,388,608 elems
    unsigned short* WqT = ws + 8388608;         //  1,048,576
    unsigned short* WkT = ws + 9437184;
    unsigned short* WvT = ws + 10485760;
    unsigned short* Qb  = ws + 0;               //  4,194,304 (over dead xcb)
    unsigned short* KFb = ws + 4194304;         //  8,388,608 (over dead xcb/W*T)
    unsigned short* WuT = ws + 12582912;        //  1,048,576 (lives to the end)
    unsigned short* Yq  = ws + 13631488;        //  4,194,304 ; reused as O
    unsigned short* Ob  = Yq;
    unsigned short* Yk  = ws + 17825792;        //  8,388,608 ; reused as VF
    unsigned short* VFb = Yk;
    unsigned short* Yv  = ws + 26214400;        //  8,388,608
    float* Mcat         = (float*)(ws + 34603008);  // 8192 floats

    const float scale = 0.17677669529663687f;               // 1024^-0.25
    const float qscale = 0.17677669529663687f * 1.4426950408889634f; // * log2(e)

    build_xcb_k<<<4096, 256, 0, stream>>>(x, ctx, xcb);
    mcat_k<<<32, 256, 0, stream>>>(mask, cmask, Mcat);
    dim3 wt(16, 16);
    wtrans_k<<<wt, 256, 0, stream>>>(Wq, WqT);
    wtrans_k<<<wt, 256, 0, stream>>>(Wk, WkT);
    wtrans_k<<<wt, 256, 0, stream>>>(Wv, WvT);
    wtrans_k<<<wt, 256, 0, stream>>>(Wu, WuT);

    gemm_bt_k<false><<<dim3(8, 64), 256, 0, stream>>>(xcb, WkT, Yk, nullptr, 64, 8192);
    gemm_bt_k<false><<<dim3(8, 64), 256, 0, stream>>>(xcb, WvT, Yv, nullptr, 64, 8192);
    gemm_bt_k<false><<<dim3(8, 32), 256, 0, stream>>>(xcb, WqT, Yq, nullptr, 16, 4096);

    ln_head_k<<<16384, 256, 0, stream>>>(Yq, Qb, qlnw, qlnb, S_LEN, qscale);
    ln_head_pack_k<<<32768, 256, 0, stream>>>(Yk, KFb, klnw, klnb, scale);
    vpack_k<<<dim3(64, 32), 256, 0, stream>>>(Yv, VFb);

    attn32_k<<<dim3(32, 32), 256, 0, stream>>>(Qb, KFb, VFb, Mcat, Ob);

    gemm_bt_k<true><<<dim3(8, 32), 256, 0, stream>>>(Ob, WuT, d_out, bu, 32, 4096);
}